// Round 14
// baseline (715.934 us; speedup 1.0000x reference)
//
#include <hip/hip_runtime.h>
#include <hip/hip_bf16.h>

#define N_NODES 100000
#define N_EDGES 1600000
// IN_C=128, HEADS=8, OUT_C=8, ACTUAL_OUT=64, EDGE_DIM=4
// 100000 = 3125 row-tiles x 32 rows exactly (no edge guards in k1)

typedef unsigned short ushort_t;
typedef __attribute__((ext_vector_type(4))) float f32x4;
typedef __attribute__((ext_vector_type(8))) short bf16x8v;

__device__ __forceinline__ float rlane(float v, int l) {
    return __int_as_float(__builtin_amdgcn_readlane(__float_as_int(v), l));
}
// f32 -> bf16 bits (round-nearest-even), and back
__device__ __forceinline__ unsigned f2bf(float f) {
    unsigned u = __float_as_uint(f);
    u += 0x7FFFu + ((u >> 16) & 1u);
    return u >> 16;
}
__device__ __forceinline__ float bf2f(unsigned b) {
    return __uint_as_float((b & 0xFFFFu) << 16);
}

// ---------------- K1 (MFMA): [h | ident] = bf16(x) @ bf16([W | res_W]) -------
__global__ __launch_bounds__(256) void k1_mfma(
    const float* __restrict__ x, const float* __restrict__ W,
    const float* __restrict__ resW, const float* __restrict__ att_src,
    const float* __restrict__ att_dst, const float* __restrict__ res_b,
    ushort_t* __restrict__ h, float* __restrict__ ident,
    float* __restrict__ a_src, float* __restrict__ a_dst)
{
    const int lane = threadIdx.x & 63;
    const int col = lane & 15;
    const int kg  = lane >> 4;

    bf16x8v bfrag[4][8];
    #pragma unroll
    for (int ks = 0; ks < 4; ++ks) {
        #pragma unroll
        for (int fc = 0; fc < 8; ++fc) {
            const int j = (fc & 3) * 16 + col;
            const float* src = (fc < 4) ? (W + j) : (resW + j);
            bf16x8v b;
            #pragma unroll
            for (int i = 0; i < 8; ++i) {
                const int k = ks * 32 + kg * 8 + i;
                b[i] = (short)f2bf(src[k * 64]);
            }
            bfrag[ks][fc] = b;
        }
    }
    float atts[4], attd[4], rb[4];
    #pragma unroll
    for (int fc = 0; fc < 4; ++fc) {
        atts[fc] = att_src[fc * 16 + col];
        attd[fc] = att_dst[fc * 16 + col];
        rb[fc]   = res_b[fc * 16 + col];
    }

    const int wid = blockIdx.x * 4 + (threadIdx.x >> 6);
    const int nw = gridDim.x * 4;
    for (int tile = wid; tile < 3125; tile += nw) {
        const int row0 = tile * 32;
        f32x4 acc[2][8];
        #pragma unroll
        for (int rt = 0; rt < 2; ++rt)
            #pragma unroll
            for (int fc = 0; fc < 8; ++fc)
                acc[rt][fc] = (f32x4){0.f, 0.f, 0.f, 0.f};

        #pragma unroll
        for (int ks = 0; ks < 4; ++ks) {
            bf16x8v afrag[2];
            #pragma unroll
            for (int rt = 0; rt < 2; ++rt) {
                const float* xr = x + (size_t)(row0 + rt * 16 + col) * 128 + ks * 32 + kg * 8;
                const float4 lo = *reinterpret_cast<const float4*>(xr);
                const float4 hi = *reinterpret_cast<const float4*>(xr + 4);
                bf16x8v a;
                a[0] = (short)f2bf(lo.x); a[1] = (short)f2bf(lo.y);
                a[2] = (short)f2bf(lo.z); a[3] = (short)f2bf(lo.w);
                a[4] = (short)f2bf(hi.x); a[5] = (short)f2bf(hi.y);
                a[6] = (short)f2bf(hi.z); a[7] = (short)f2bf(hi.w);
                afrag[rt] = a;
            }
            #pragma unroll
            for (int fc = 0; fc < 8; ++fc) {
                acc[0][fc] = __builtin_amdgcn_mfma_f32_16x16x32_bf16(
                    afrag[0], bfrag[ks][fc], acc[0][fc], 0, 0, 0);
                acc[1][fc] = __builtin_amdgcn_mfma_f32_16x16x32_bf16(
                    afrag[1], bfrag[ks][fc], acc[1][fc], 0, 0, 0);
            }
        }

        #pragma unroll
        for (int rt = 0; rt < 2; ++rt) {
            #pragma unroll
            for (int fc = 0; fc < 8; ++fc) {
                #pragma unroll
                for (int r = 0; r < 4; ++r) {
                    const int row = row0 + rt * 16 + kg * 4 + r;
                    const float val = acc[rt][fc][r];
                    if (fc < 4) {
                        h[(size_t)row * 64 + fc * 16 + col] = (ushort_t)f2bf(val);
                        float ps = val * atts[fc];
                        float pd = val * attd[fc];
                        ps += __shfl_xor(ps, 1); ps += __shfl_xor(ps, 2); ps += __shfl_xor(ps, 4);
                        pd += __shfl_xor(pd, 1); pd += __shfl_xor(pd, 2); pd += __shfl_xor(pd, 4);
                        if ((lane & 7) == 0) {
                            const int hd = fc * 2 + (col >> 3);
                            a_src[row * 8 + hd] = ps;
                            a_dst[row * 8 + hd] = pd;
                        }
                    } else {
                        ident[(size_t)row * 64 + (fc - 4) * 16 + col] = val + rb[fc - 4];
                    }
                }
            }
        }
    }
}

// ---------------- K2a: degree histogram over dst --------------------------
__global__ __launch_bounds__(256) void k2a_hist(const int* __restrict__ ei,
                                                int* __restrict__ deg) {
    for (int e = blockIdx.x * 256 + threadIdx.x; e < N_EDGES; e += gridDim.x * 256)
        atomicAdd(&deg[ei[N_EDGES + e]], 1);
}

// ---------------- K2b: exclusive scan (single block, 1024 thr) -------------
__global__ __launch_bounds__(1024) void k2b_scan(const int* __restrict__ deg,
                                                 int* __restrict__ roff,
                                                 int* __restrict__ wcur) {
    __shared__ int part[1024];
    __shared__ int pre[1024];
    __shared__ int stot;
    const int tid = threadIdx.x;
    const int start = tid * 98;
    const int end = (start + 98 < N_NODES) ? start + 98 : N_NODES;
    int local = 0;
    for (int i = start; i < end; ++i) local += deg[i];
    part[tid] = local;
    __syncthreads();
    if (tid == 0) {
        int run = 0;
        for (int t = 0; t < 1024; ++t) { pre[t] = run; run += part[t]; }
        stot = run;
    }
    __syncthreads();
    int run = pre[tid];
    for (int i = start; i < end; ++i) {
        roff[i] = run; wcur[i] = run; run += deg[i];
    }
    if (tid == 0) roff[N_NODES] = stot;
}

// ---------------- K2c: scatter edges into dst-sorted arrays ----------------
__global__ __launch_bounds__(256) void k2c_scatter(
    const int* __restrict__ ei, const float* __restrict__ ea,
    int* __restrict__ wcur, int* __restrict__ es, uint2* __restrict__ epk) {
    for (int e = blockIdx.x * 256 + threadIdx.x; e < N_EDGES; e += gridDim.x * 256) {
        const int s = ei[e];
        const int d = ei[N_EDGES + e];
        const float4 v = *reinterpret_cast<const float4*>(ea + (size_t)e * 4);
        const int pos = atomicAdd(&wcur[d], 1);
        es[pos] = s;
        uint2 p;
        p.x = f2bf(v.x) | (f2bf(v.y) << 16);
        p.y = f2bf(v.z) | (f2bf(v.w) << 16);
        epk[pos] = p;
    }
}

// ---------------- K2d: per-dst register accumulate (no output atomics) -----
// Wave per dst. Stage <=64 edges into lane regs (coalesced), then 8-deep
// readlane+gather groups (k2's proven pattern). v = acc/den + bias -> bf16
// store; BN partial stats via LDS block-reduce -> 2 atomics per channel/block.
__global__ __launch_bounds__(256) void k2d_accum(
    const int* __restrict__ roff, const int* __restrict__ es,
    const uint2* __restrict__ epk, const ushort_t* __restrict__ h,
    const float* __restrict__ a_src, const float* __restrict__ a_dst,
    const float* __restrict__ W_edge, const float* __restrict__ att_edge,
    const float* __restrict__ bias,
    ushort_t* __restrict__ out16, float* __restrict__ bn_acc)
{
    const int tid = threadIdx.x;
    const int lane = tid & 63;
    const int hd = lane >> 3;
    // AE fold: ae_d = sum_c W_edge[d][hd*8+c] * att_edge[hd][c]
    float ae0 = 0.f, ae1 = 0.f, ae2 = 0.f, ae3 = 0.f;
    #pragma unroll
    for (int c2 = 0; c2 < 8; ++c2) {
        const float a = att_edge[hd * 8 + c2];
        ae0 = fmaf(W_edge[0 * 64 + hd * 8 + c2], a, ae0);
        ae1 = fmaf(W_edge[1 * 64 + hd * 8 + c2], a, ae1);
        ae2 = fmaf(W_edge[2 * 64 + hd * 8 + c2], a, ae2);
        ae3 = fmaf(W_edge[3 * 64 + hd * 8 + c2], a, ae3);
    }
    const float bia = bias[lane];
    float s1 = 0.f, s2 = 0.f;

    const int gw = blockIdx.x * 4 + (tid >> 6);
    const int nw = gridDim.x * 4;
    for (int d = gw; d < N_NODES; d += nw) {
        const int row = roff[d];
        const int dg = roff[d + 1] - row;
        const float adv = a_dst[d * 8 + hd];
        float acc = 0.f, den = 0.f;

        int vs = 0; uint2 vp; vp.x = 0; vp.y = 0;
        if (lane < dg) { vs = es[row + lane]; vp = epk[row + lane]; }
        const int m = dg < 64 ? dg : 64;

        for (int g = 0; g < m; g += 8) {
            int sj[8]; float dj[8];
            #pragma unroll
            for (int j = 0; j < 8; ++j) {
                int idx = g + j; const bool ok = idx < m; idx = ok ? idx : 0;
                sj[j] = __builtin_amdgcn_readlane(vs, idx);
                const unsigned px = (unsigned)__builtin_amdgcn_readlane((int)vp.x, idx);
                const unsigned py = (unsigned)__builtin_amdgcn_readlane((int)vp.y, idx);
                float dd = bf2f(px) * ae0 + bf2f(px >> 16) * ae1
                         + bf2f(py) * ae2 + bf2f(py >> 16) * ae3;
                dj[j] = ok ? dd : -1e30f;   // invalid -> exp(leaky(-inf)) = 0
            }
            float as8[8], hv[8];
            #pragma unroll
            for (int j = 0; j < 8; ++j) {   // 16 independent loads in flight
                as8[j] = a_src[sj[j] * 8 + hd];
                hv[j]  = bf2f(h[(size_t)sj[j] * 64 + lane]);
            }
            #pragma unroll
            for (int j = 0; j < 8; ++j) {
                float logit = as8[j] + adv + dj[j];
                logit = logit > 0.f ? logit : 0.2f * logit;  // leaky_relu 0.2
                const float num = __expf(logit);             // 0 for padded j
                den += num;
                acc = fmaf(num, hv[j], acc);
            }
        }
        // tail for deg > 64 (Poisson(16): effectively never, kept for rigor)
        for (int i = 64; i < dg; ++i) {
            const int s = es[row + i];
            const uint2 p = epk[row + i];
            float logit = a_src[s * 8 + hd] + adv
                        + bf2f(p.x) * ae0 + bf2f(p.x >> 16) * ae1
                        + bf2f(p.y) * ae2 + bf2f(p.y >> 16) * ae3;
            logit = logit > 0.f ? logit : 0.2f * logit;
            const float num = __expf(logit);
            den += num;
            acc = fmaf(num, bf2f(h[(size_t)s * 64 + lane]), acc);
        }

        const float v = acc / (den + 1e-16f) + bia;
        out16[(size_t)d * 64 + lane] = (ushort_t)f2bf(v);
        s1 += v; s2 += v * v;
    }

    __shared__ float r1[256], r2[256];
    r1[tid] = s1; r2[tid] = s2;
    __syncthreads();
    if (tid < 64) {
        s1 = r1[tid] + r1[tid + 64] + r1[tid + 128] + r1[tid + 192];
        s2 = r2[tid] + r2[tid + 64] + r2[tid + 128] + r2[tid + 192];
        atomicAdd(&bn_acc[tid], s1);
        atomicAdd(&bn_acc[64 + tid], s2);
    }
}

// ---------------- K4: BN affine + ELU + residual (ident in d_out) ----------
__global__ __launch_bounds__(256) void k4_final(
    float* __restrict__ out, const ushort_t* __restrict__ out16,
    const float* __restrict__ bn_acc, const float* __restrict__ bn_w,
    const float* __restrict__ bn_b)
{
    const int tid = threadIdx.x;
    const int c = tid & 63;
    const float inv_n = 1.0f / (float)N_NODES;
    const float mean = bn_acc[c] * inv_n;
    const float var = bn_acc[64 + c] * inv_n - mean * mean;   // biased var
    const float sc = bn_w[c] * rsqrtf(var + 1e-5f);
    const float sh = bn_b[c] - mean * sc;
    const int stride = gridDim.x * 4;
    for (int n = blockIdx.x * 4 + (tid >> 6); n < N_NODES; n += stride) {
        float v = bf2f(out16[(size_t)n * 64 + c]);   // has bias already
        v = v * sc + sh;
        v = v > 0.f ? v : __expf(v) - 1.f;            // ELU
        out[(size_t)n * 64 + c] = v + out[(size_t)n * 64 + c];  // + ident
    }
}

extern "C" void kernel_launch(void* const* d_in, const int* in_sizes, int n_in,
                              void* d_out, int out_size, void* d_ws, size_t ws_size,
                              hipStream_t stream) {
    const float* x        = (const float*)d_in[0];
    const int*   ei       = (const int*)  d_in[1];
    const float* ea       = (const float*)d_in[2];
    const float* W        = (const float*)d_in[3];
    const float* att_src  = (const float*)d_in[4];
    const float* att_dst  = (const float*)d_in[5];
    const float* W_edge   = (const float*)d_in[6];
    const float* att_edge = (const float*)d_in[7];
    const float* bias     = (const float*)d_in[8];
    const float* bn_w     = (const float*)d_in[9];
    const float* bn_b     = (const float*)d_in[10];
    const float* res_W    = (const float*)d_in[11];
    const float* res_b    = (const float*)d_in[12];

    char* ws = (char*)d_ws;
    size_t off = 0;
    ushort_t* h     = (ushort_t*)(ws + off); off += (size_t)N_NODES * 64 * 2;
    float* a_src    = (float*)(ws + off); off += (size_t)N_NODES * 8 * 4;
    float* a_dst    = (float*)(ws + off); off += (size_t)N_NODES * 8 * 4;
    ushort_t* out16 = (ushort_t*)(ws + off); off += (size_t)N_NODES * 64 * 2;
    int* es         = (int*)(ws + off); off += (size_t)N_EDGES * 4;
    uint2* epk      = (uint2*)(ws + off); off += (size_t)N_EDGES * 8;
    int* roff       = (int*)(ws + off); off += (size_t)(N_NODES + 1) * 4;
    char* zstart = ws + off;
    int* deg        = (int*)(ws + off); off += (size_t)N_NODES * 4;
    int* wcur       = (int*)(ws + off); off += (size_t)N_NODES * 4;
    float* bn_acc   = (float*)(ws + off); off += 128 * 4;
    size_t zbytes = (size_t)((ws + off) - zstart);

    float* ident = (float*)d_out;  // K1 writes residual GEMV here; K4 fuses in place

    (void)hipMemsetAsync(zstart, 0, zbytes, stream);
    k1_mfma<<<512, 256, 0, stream>>>(
        x, W, res_W, att_src, att_dst, res_b, h, ident, a_src, a_dst);
    k2a_hist<<<2048, 256, 0, stream>>>(ei, deg);
    k2b_scan<<<1, 1024, 0, stream>>>(deg, roff, wcur);
    k2c_scatter<<<2048, 256, 0, stream>>>(ei, ea, wcur, es, epk);
    k2d_accum<<<2048, 256, 0, stream>>>(roff, es, epk, h, a_src, a_dst,
                                        W_edge, att_edge, bias, out16, bn_acc);
    k4_final<<<2048, 256, 0, stream>>>((float*)d_out, out16, bn_acc, bn_w, bn_b);
}